// Round 10
// baseline (44.843 us; speedup 1.0000x reference)
//
#include <hip/hip_runtime.h>

namespace {
constexpr int kB = 32, kT = 30, kD = 512, kL = 196;
constexpr float kK = 2.8853900817779268f;  // 2*log2(e)
constexpr size_t kEgN = (size_t)kB * kT * kD;      // 491,520
constexpr size_t kFN = (size_t)kB * 128 * kL * 4;  // 3,211,264
constexpr size_t kGsz = (size_t)kB * kT * kL;      // 188,160

// vwi/u + vwj/v = (vwi*v + vwj*u) * rcp(u*v): 1 rcp per 2 elements
#define PAIR(ex, ey, fx, fy, vx, vy, acc)                                   \
  {                                                                         \
    const float u_ = fmaf(ex, fx, 1.f);                                     \
    const float v_ = fmaf(ey, fy, 1.f);                                     \
    acc = fmaf(fmaf(v_, vx, u_ * vy), __builtin_amdgcn_rcpf(u_ * v_), acc); \
  }

// blocks [0,120): Eg = 2^(kK(x+w)).
// blocks [120,1144): imgF4[b][dq][l][j] = 2^(kK*img[b][l][4dq+j]) with
// l-contiguous (coalesced) writes: thread=(dq4:4, l:64), 4 l-iters.
__global__ __launch_bounds__(256) void k_prep(const float* __restrict__ x,
                                              const float* __restrict__ w,
                                              const float* __restrict__ img,
                                              float* __restrict__ Eg,
                                              float* __restrict__ imgF4) {
  const int bx = blockIdx.x;
  if (bx < 120) {
    const float4* x4 = (const float4*)x;
    const float4* w4 = (const float4*)w;
    float4* e4 = (float4*)Eg;
#pragma unroll
    for (int k = 0; k < 4; ++k) {
      const int i = bx * 256 + threadIdx.x + k * 120 * 256;
      const float4 a = x4[i], b = w4[i];
      float4 r;
      r.x = __builtin_amdgcn_exp2f(kK * (a.x + b.x));
      r.y = __builtin_amdgcn_exp2f(kK * (a.y + b.y));
      r.z = __builtin_amdgcn_exp2f(kK * (a.z + b.z));
      r.w = __builtin_amdgcn_exp2f(kK * (a.w + b.w));
      e4[i] = r;
    }
  } else {
    const int n = bx - 120;  // 1024 = 32 dqg x 32 b
    const int dqg = n & 31, b = n >> 5;
    const int dq = dqg * 4 + (threadIdx.x & 3);
    const int lIdx = threadIdx.x >> 2;  // 0..63
#pragma unroll
    for (int i = 0; i < 4; ++i) {
      const int l = lIdx + i * 64;
      if (l < kL) {
        const float4 v =
            *(const float4*)(img + ((size_t)(b * kL + l)) * kD + 4 * dq);
        float4 o;
        o.x = __builtin_amdgcn_exp2f(kK * v.x);
        o.y = __builtin_amdgcn_exp2f(kK * v.y);
        o.z = __builtin_amdgcn_exp2f(kK * v.z);
        o.w = __builtin_amdgcn_exp2f(kK * v.w);
        *(float4*)(imgF4 + (((size_t)(b * 128 + dq)) * kL + l) * 4) = o;
      }
    }
  }
}

// g8[dq][b][t][l] (l<192) = sum over 64 d of vw_d/(1+E*F).
// 6144 one-wave blocks; XCD b-affinity (bg = n&7). Wave = 4t x 64l x 64d.
// E/vw loaded via VMEM (lane-opaque zero) -> deep vmcnt pipelining, not s_load.
__global__ __launch_bounds__(64) void k_scoreT(const float* __restrict__ Eg,
                                               const float* __restrict__ imgF4,
                                               const float* __restrict__ vw,
                                               float* __restrict__ g8) {
  const int lane = threadIdx.x;
  int zz;
  asm volatile("v_mov_b32 %0, 0" : "=v"(zz));  // opaque 0: forces VGPR addressing
  int n = blockIdx.x;
  const int bg = n & 7;
  int m = n >> 3;  // 768 = 4 bi * 3 lc * 8 tq * 8 dq
  const int bi = m & 3; m >>= 2;
  const int lc = m % 3; m /= 3;
  const int tq = m & 7;
  const int dq = m >> 3;
  const int b = bg * 4 + bi;
  const int t0 = (tq < 7) ? tq * 4 : 26;  // rows 26,27 dup'd (bit-identical)
  const float* Fp =
      imgF4 + (((size_t)(b * 128 + dq * 16)) * kL + lc * 64 + lane) * 4;
  const float* e0 = Eg + ((size_t)(b * kT + t0)) * kD + dq * 64 + zz;
  const float* e1 = e0 + kD;
  const float* e2 = e0 + 2 * kD;
  const float* e3 = e0 + 3 * kD;
  const float* vp = vw + dq * 64 + zz;
  float a0 = 0.f, a1 = 0.f, a2 = 0.f, a3 = 0.f;
  auto loadF = [&](float4* dst, int bb) {
#pragma unroll
    for (int j = 0; j < 8; ++j)
      dst[j] = *(const float4*)(Fp + (size_t)(bb * 8 + j) * (kL * 4));
  };
  auto compF = [&](const float4* f, int bb) {
#pragma unroll
    for (int j = 0; j < 8; ++j) {
      const int s = bb * 8 + j;
      const float4 vv = *(const float4*)(vp + 4 * s);
      const float4 E0 = *(const float4*)(e0 + 4 * s);
      const float4 E1 = *(const float4*)(e1 + 4 * s);
      const float4 E2 = *(const float4*)(e2 + 4 * s);
      const float4 E3 = *(const float4*)(e3 + 4 * s);
      PAIR(E0.x, E0.y, f[j].x, f[j].y, vv.x, vv.y, a0);
      PAIR(E0.z, E0.w, f[j].z, f[j].w, vv.z, vv.w, a0);
      PAIR(E1.x, E1.y, f[j].x, f[j].y, vv.x, vv.y, a1);
      PAIR(E1.z, E1.w, f[j].z, f[j].w, vv.z, vv.w, a1);
      PAIR(E2.x, E2.y, f[j].x, f[j].y, vv.x, vv.y, a2);
      PAIR(E2.z, E2.w, f[j].z, f[j].w, vv.z, vv.w, a2);
      PAIR(E3.x, E3.y, f[j].x, f[j].y, vv.x, vv.y, a3);
      PAIR(E3.z, E3.w, f[j].z, f[j].w, vv.z, vv.w, a3);
    }
  };
  float4 fA[8], fB[8];
  loadF(fA, 0);
  loadF(fB, 1);
  compF(fA, 0);
  compF(fB, 1);
  float* gp =
      g8 + (size_t)dq * kGsz + ((size_t)(b * kT + t0)) * kL + lc * 64 + lane;
  gp[0] = a0;
  gp[kL] = a1;
  gp[2 * kL] = a2;
  gp[3 * kL] = a3;
}

// Merged softmax + context. 384 blocks = (bg&7 XCD-affine, bi, tg:6, dh:2).
// Phase 1 (4 waves, rows r=wv and r+4): softmax over l for 5 t rows -> LDS
// AL[l][q] (float4-packed). Phase 2: thread=d (256 d-half), 8-deep img dbuf.
__global__ __launch_bounds__(256) void k_actx2(const float* __restrict__ img,
                                               const float* __restrict__ g8,
                                               const float* __restrict__ Eg,
                                               const float* __restrict__ vw,
                                               float* __restrict__ out) {
  __shared__ __align__(16) float AL[200][8];  // [l][q], cols 0..4 used
  int n = blockIdx.x;
  const int bg = n & 7;
  int m = n >> 3;  // 48 = 4 bi * 6 tg * 2 dh
  const int bi = m & 3; m >>= 2;
  const int tg = m % 6;
  const int dh = m / 6;
  const int b = bg * 4 + bi;
  const int t0 = tg * 5, d0 = dh * 256;
  const int tid = threadIdx.x;
  const int lane = tid & 63, wv = tid >> 6;
  // ---- phase 1: rows {wv} and (wv==0: row 4) ----
  for (int r = wv; r < 5; r += 4) {
    const int t = t0 + r;
    // tail l=192..195: lane=(l4:4, dc:16), each lane sums 32 d
    const int l4 = lane & 3, dc = lane >> 2;
    const float* ir = img + ((size_t)(b * kL + 192 + l4)) * kD + dc * 32;
    const float* er = Eg + ((size_t)(b * kT + t)) * kD + dc * 32;
    const float* vr = vw + dc * 32;
    float tg2 = 0.f;
#pragma unroll
    for (int k = 0; k < 8; ++k) {
      const float4 iv = *(const float4*)(ir + 4 * k);
      const float4 ev = *(const float4*)(er + 4 * k);
      const float4 vv = *(const float4*)(vr + 4 * k);
      PAIR(ev.x, ev.y, __builtin_amdgcn_exp2f(kK * iv.x),
           __builtin_amdgcn_exp2f(kK * iv.y), vv.x, vv.y, tg2);
      PAIR(ev.z, ev.w, __builtin_amdgcn_exp2f(kK * iv.z),
           __builtin_amdgcn_exp2f(kK * iv.w), vv.z, vv.w, tg2);
    }
#pragma unroll
    for (int mm = 4; mm < 64; mm <<= 1) tg2 += __shfl_xor(tg2, mm, 64);
    const size_t base = ((size_t)(b * kT + t)) * kL;
    float q0 = 0.f, q1 = 0.f, q2 = 0.f;
#pragma unroll
    for (int p = 0; p < 8; ++p) {
      const float* gp = g8 + (size_t)p * kGsz + base;
      q0 += gp[lane];
      q1 += gp[lane + 64];
      q2 += gp[lane + 128];
    }
    q0 *= kK; q1 *= kK; q2 *= kK;
    float q3 = (lane < 4) ? tg2 * kK : __builtin_inff();
    float mn = fminf(fminf(q0, q1), fminf(q2, q3));
#pragma unroll
    for (int mm = 1; mm < 64; mm <<= 1) mn = fminf(mn, __shfl_xor(mn, mm, 64));
    const float e0 = __builtin_amdgcn_exp2f(mn - q0);
    const float e1 = __builtin_amdgcn_exp2f(mn - q1);
    const float e2 = __builtin_amdgcn_exp2f(mn - q2);
    const float e3 = (lane < 4) ? __builtin_amdgcn_exp2f(mn - q3) : 0.f;
    float s = e0 + e1 + e2 + e3;
#pragma unroll
    for (int mm = 1; mm < 64; mm <<= 1) s += __shfl_xor(s, mm, 64);
    const float rs = __builtin_amdgcn_rcpf(s);
    AL[lane][r] = e0 * rs;
    AL[lane + 64][r] = e1 * rs;
    AL[lane + 128][r] = e2 * rs;
    if (lane < 4) AL[lane + 192][r] = e3 * rs;
  }
  __syncthreads();
  // ---- phase 2: context GEMV; thread = one d column ----
  const int d = d0 + tid;
  const float* ip = img + (size_t)b * kL * kD + d;
  float ac0 = 0.f, ac1 = 0.f, ac2 = 0.f, ac3 = 0.f, ac4 = 0.f;
  float fA[8], fB[8];
  auto loadI = [&](float* f, int bb) {
#pragma unroll
    for (int j = 0; j < 8; ++j) f[j] = ip[(size_t)(bb * 8 + j) * kD];
  };
  auto compI = [&](const float* f, int bb) {
#pragma unroll
    for (int j = 0; j < 8; ++j) {
      const int l = bb * 8 + j;
      const float4 a03 = *(const float4*)&AL[l][0];  // broadcast
      const float a4 = AL[l][4];
      ac0 = fmaf(f[j], a03.x, ac0);
      ac1 = fmaf(f[j], a03.y, ac1);
      ac2 = fmaf(f[j], a03.z, ac2);
      ac3 = fmaf(f[j], a03.w, ac3);
      ac4 = fmaf(f[j], a4, ac4);
    }
  };
  loadI(fA, 0);
#pragma unroll
  for (int bb = 0; bb < 24; ++bb) {
    if (bb + 1 < 24) {
      if ((bb + 1) & 1) loadI(fB, bb + 1); else loadI(fA, bb + 1);
    }
    if (bb & 1) compI(fB, bb); else compI(fA, bb);
  }
#pragma unroll
  for (int l = 192; l < 196; ++l) {
    const float v = ip[(size_t)l * kD];
    const float4 a03 = *(const float4*)&AL[l][0];
    const float a4 = AL[l][4];
    ac0 = fmaf(v, a03.x, ac0);
    ac1 = fmaf(v, a03.y, ac1);
    ac2 = fmaf(v, a03.z, ac2);
    ac3 = fmaf(v, a03.w, ac3);
    ac4 = fmaf(v, a4, ac4);
  }
  float* op = out + ((size_t)(b * kT + t0)) * kD + d;
  op[0] = ac0;
  op[kD] = ac1;
  op[2 * kD] = ac2;
  op[3 * kD] = ac3;
  op[4 * kD] = ac4;
}
}  // namespace

extern "C" void kernel_launch(void* const* d_in, const int* in_sizes, int n_in,
                              void* d_out, int out_size, void* d_ws, size_t ws_size,
                              hipStream_t stream) {
  const float* x = (const float*)d_in[0];
  const float* wordemb = (const float*)d_in[1];
  const float* img = (const float*)d_in[2];
  const float* vw = (const float*)d_in[3];
  // v_b (d_in[4]) cancels in the softmax along with sum(v_w) — unused by design.
  float* out = (float*)d_out;
  float* Eg = (float*)d_ws;      // 1.97 MB
  float* imgF4 = Eg + kEgN;      // 12.8 MB
  float* g8 = imgF4 + kFN;       // 6.02 MB
  hipLaunchKernelGGL(k_prep, dim3(1144), dim3(256), 0, stream, x, wordemb, img,
                     Eg, imgF4);
  hipLaunchKernelGGL(k_scoreT, dim3(6144), dim3(64), 0, stream, Eg, imgF4, vw,
                     g8);
  hipLaunchKernelGGL(k_actx2, dim3(384), dim3(256), 0, stream, img, g8, Eg, vw,
                     out);
}